// Round 6
// baseline (104.955 us; speedup 1.0000x reference)
//
#include <hip/hip_runtime.h>
#include <hip/hip_bf16.h>
#include <math.h>
#include <stdint.h>

#define EPS 1e-5f

typedef __attribute__((ext_vector_type(8))) short bf16x8;
typedef __attribute__((ext_vector_type(16))) float f32x16;

__device__ __forceinline__ ushort f2bf(float f) {
    union { float f; unsigned u; } v; v.f = f;
    unsigned r = (v.u + 0x7FFFu + ((v.u >> 16) & 1u)) >> 16;
    return (ushort)r;
}

__device__ __forceinline__ void dma16(const void* g, void* l) {
    __builtin_amdgcn_global_load_lds(
        (__attribute__((address_space(1))) const void*)(uintptr_t)g,
        (__attribute__((address_space(3))) void*)(uintptr_t)l,
        16, 0, 0);
}

// ---------------------------------------------------------------------------
// Kernel 1: transpose x -> xT[b][y 66][c 66][ic 128] bf16 (borders zero),
// plus pooling partials [b][y][ic].  grid = 2048, XCD-grouped by sample.
// LDS: T2[col][ic] fp32, stride 132 (writes 2-way free, float4 reads ~floor).
// Global writes: 4 lanes cover 256B contiguous (coalesced).
// ---------------------------------------------------------------------------
__global__ __launch_bounds__(256) void transpose_kernel(const float* __restrict__ x,
                                                        ushort* __restrict__ xT,
                                                        float* __restrict__ partial) {
    __shared__ float T2[64][132];
    int bid = blockIdx.x;
    int b = (bid & 7) * 4 + (bid >> 9);
    int y = (bid >> 3) & 63;
    int t = threadIdx.x;

    // phase 1: load x[b][ic][y][:], sum, stash transposed in LDS
    int ic2 = t >> 1, half = t & 1;
    const float4* src = (const float4*)(x + (((size_t)b * 128 + ic2) * 64 + y) * 64 + half * 32);
    float s = 0.f;
#pragma unroll
    for (int i = 0; i < 8; ++i) {
        float4 v = src[i];
        int c0 = half * 32 + i * 4;
        T2[c0][ic2] = v.x; T2[c0 + 1][ic2] = v.y; T2[c0 + 2][ic2] = v.z; T2[c0 + 3][ic2] = v.w;
        s += v.x + v.y + v.z + v.w;
    }
    s += __shfl_xor(s, 1, 64);
    if (half == 0) partial[((size_t)b * 64 + y) * 128 + ic2] = s;
    __syncthreads();

    // phase 2: read float4 runs along ic, convert, write coalesced
    int col = t >> 2, icq = t & 3;
    const float4* row = (const float4*)&T2[col][icq * 32];
    uint pk[16];
#pragma unroll
    for (int m = 0; m < 8; ++m) {
        float4 v = row[m];
        pk[2 * m]     = (uint)f2bf(v.x) | ((uint)f2bf(v.y) << 16);
        pk[2 * m + 1] = (uint)f2bf(v.z) | ((uint)f2bf(v.w) << 16);
    }
    ushort* dst = xT + (((size_t)(b * 66 + y + 1)) * 66 + col + 1) * 128 + icq * 32;
    ((uint4*)dst)[0] = make_uint4(pk[0], pk[1], pk[2], pk[3]);
    ((uint4*)dst)[1] = make_uint4(pk[4], pk[5], pk[6], pk[7]);
    ((uint4*)dst)[2] = make_uint4(pk[8], pk[9], pk[10], pk[11]);
    ((uint4*)dst)[3] = make_uint4(pk[12], pk[13], pk[14], pk[15]);

    uint4 z = make_uint4(0, 0, 0, 0);
    if (y == 0) {
        uint4* row0 = (uint4*)(xT + ((size_t)b * 66 + 0) * 66 * 128);
        for (int i = t; i < 1056; i += 256) row0[i] = z;
    }
    if (y == 63) {
        uint4* row65 = (uint4*)(xT + ((size_t)b * 66 + 65) * 66 * 128);
        for (int i = t; i < 1056; i += 256) row65[i] = z;
    }
    if (t < 32) {
        int c = (t >> 4) * 65;
        int i = t & 15;
        *(uint4*)(xT + (((size_t)(b * 66 + y + 1)) * 66 + c) * 128 + i * 8) = z;
    }
}

// ---------------------------------------------------------------------------
// Kernel 2: fused reduce + SE MLP -> att[32,4].  grid = 32.
// ---------------------------------------------------------------------------
__global__ __launch_bounds__(256) void sefuse_kernel(const float* __restrict__ partial,
                                                     const float* __restrict__ se_w1,
                                                     const float* __restrict__ gn1_s, const float* __restrict__ gn1_b,
                                                     const float* __restrict__ se_w2,
                                                     const float* __restrict__ gn2_s, const float* __restrict__ gn2_b,
                                                     float* __restrict__ att) {
    __shared__ float sA[256];
    __shared__ float pl[128];
    __shared__ float h1s[8];
    int b = blockIdx.x;
    int t = threadIdx.x;
    int ic = t & 127, hf = t >> 7;

    const float* p = partial + ((size_t)b * 64 + hf * 32) * 128 + ic;
    float s = 0.f;
#pragma unroll
    for (int k = 0; k < 32; ++k) s += p[k * 128];
    sA[t] = s;
    __syncthreads();
    if (t < 128) pl[t] = (sA[t] + sA[t + 128]) * (1.0f / 4096.0f);
    __syncthreads();
    if (t < 8) {
        float s1 = 0.f;
        for (int c = 0; c < 128; ++c) s1 += pl[c] * se_w1[t * 128 + c];
        h1s[t] = s1;
    }
    __syncthreads();
    if (t == 0) {
        float h1[8];
#pragma unroll
        for (int j = 0; j < 8; ++j) h1[j] = h1s[j];
        float m = 0.f;
#pragma unroll
        for (int j = 0; j < 8; ++j) m += h1[j];
        m *= 0.125f;
        float var = 0.f;
#pragma unroll
        for (int j = 0; j < 8; ++j) { float d = h1[j] - m; var += d * d; }
        var *= 0.125f;
        float inv = rsqrtf(var + EPS);
#pragma unroll
        for (int j = 0; j < 8; ++j) {
            float tt = (h1[j] - m) * inv * gn1_s[j] + gn1_b[j];
            float sp = (tt > 20.f) ? tt : log1pf(expf(tt));
            h1[j] = tt * tanhf(sp);
        }
        float h2[4];
#pragma unroll
        for (int k = 0; k < 4; ++k) {
            float s2 = 0.f;
#pragma unroll
            for (int j = 0; j < 8; ++j) s2 += h1[j] * se_w2[k * 8 + j];
            h2[k] = s2;
        }
        float m2 = 0.25f * (h2[0] + h2[1] + h2[2] + h2[3]);
        float v2 = 0.f;
#pragma unroll
        for (int k = 0; k < 4; ++k) { float d = h2[k] - m2; v2 += d * d; }
        v2 *= 0.25f;
        float inv2 = rsqrtf(v2 + EPS);
#pragma unroll
        for (int k = 0; k < 4; ++k) {
            float tt = (h2[k] - m2) * inv2 * gn2_s[k] + gn2_b[k];
            att[b * 4 + k] = 1.0f / (1.0f + expf(-tt));
        }
    }
}

// ---------------------------------------------------------------------------
// Kernel 3: aggregate weights -> bf16, rotated-chunk A layout.
// Per (b, tap= h*9+s): 16 KB block of 1024 chunks (16B).  Chunk for (oc, g):
// index = oc*8 + ((g + oc) & 7), content = ic [h*64+g*8, +8) of row oc.
// grid = 288 (4 replicas x 72); replica handles 8 samples.
// ---------------------------------------------------------------------------
__global__ __launch_bounds__(256) void aggw_kernel(const float* __restrict__ weight,
                                                   const float* __restrict__ att,
                                                   ushort* __restrict__ aggw) {
    int tq = (blockIdx.x % 72) * 256 + threadIdx.x;   // chunk id in sample: 0..18431
    int rep = blockIdx.x / 72;                         // 0..3 -> samples rep*8..rep*8+7
    int tap = tq >> 10;                                // 0..17
    int within = tq & 1023;
    int oc = within >> 3;
    int p = within & 7;
    int g = (p - oc) & 7;
    int h = tap / 9, s = tap % 9;
    int ic0 = h * 64 + g * 8;

    float wv[4][8];
#pragma unroll
    for (int k = 0; k < 4; ++k)
#pragma unroll
        for (int j = 0; j < 8; ++j)
            wv[k][j] = weight[(((size_t)(k * 128 + oc)) * 128 + ic0 + j) * 9 + s];

    for (int b = rep * 8; b < rep * 8 + 8; ++b) {
        float a0 = att[b * 4 + 0], a1 = att[b * 4 + 1], a2 = att[b * 4 + 2], a3 = att[b * 4 + 3];
        uint pk[4];
#pragma unroll
        for (int q = 0; q < 4; ++q) {
            float f0 = a0 * wv[0][2 * q] + a1 * wv[1][2 * q] + a2 * wv[2][2 * q] + a3 * wv[3][2 * q];
            float f1 = a0 * wv[0][2 * q + 1] + a1 * wv[1][2 * q + 1] + a2 * wv[2][2 * q + 1] + a3 * wv[3][2 * q + 1];
            pk[q] = (uint)f2bf(f0) | ((uint)f2bf(f1) << 16);
        }
        *(uint4*)(aggw + (size_t)b * 147456 + (size_t)tq * 8) = make_uint4(pk[0], pk[1], pk[2], pk[3]);
    }
}

// ---------------------------------------------------------------------------
// Kernel 4: implicit-GEMM conv, mfma_f32_32x32x16_bf16.
// grid 512 = 32 b * 16 tiles (4 rows); block 512 = 8 waves (wm: oc-64, wn: row).
// Wave = 64 oc x 64 px (1 row), acc[2][2].  2 blocks/CU -> 4 waves/SIMD.
// B in LDS (rotation slots), A in registers with depth-1 tap prefetch.
// ---------------------------------------------------------------------------
__global__ __launch_bounds__(512, 4) void conv_kernel(const ushort* __restrict__ xT,
                                                      const ushort* __restrict__ aggw,
                                                      const float* __restrict__ att,
                                                      const float* __restrict__ bias,
                                                      float* __restrict__ out) {
    __shared__ ushort ldsB[396 * 64];                 // 6 rows x 66 cols x 8 slots x 16B = 50688 B

    int bid = blockIdx.x;
    int xcd = bid & 7;
    int idx = bid >> 3;                                // 0..63
    int b = xcd * 4 + (idx >> 4);                      // 4 samples per XCD
    int tile = idx & 15;
    int y0 = tile * 4;

    int tid = threadIdx.x;
    int l = tid & 63, w = tid >> 6;
    int wm = w & 1, wn = w >> 1;                       // wm: oc-64 half, wn: row 0..3
    int l31 = l & 31, lhi = l >> 5;

    const ushort* xTb = xT + ((size_t)(b * 66 + y0)) * 66 * 128;  // halo rows y0..y0+5
    const ushort* Asmp = aggw + (size_t)b * 147456;

    // per-lane A offsets/rotations: oc(mi) = wm*64 + mi*32 + l31
    int ocofs[2], rotA[2];
#pragma unroll
    for (int mi = 0; mi < 2; ++mi) {
        int oc = wm * 64 + mi * 32 + l31;
        ocofs[mi] = oc * 64;
        rotA[mi] = (lhi + oc) & 7;
    }
    // B cell bases: ch in {0,1}
    int CB[2];
#pragma unroll
    for (int ch = 0; ch < 2; ++ch) CB[ch] = wn * 66 + ch * 32 + l31;
    int rotB = (l31 + lhi) & 7;

    f32x16 acc[2][2];
#pragma unroll
    for (int mi = 0; mi < 2; ++mi)
#pragma unroll
        for (int ch = 0; ch < 2; ++ch)
#pragma unroll
            for (int q = 0; q < 16; ++q) acc[mi][ch][q] = 0.f;

    // ---- prefetch A tap 0 ----
    bf16x8 a[2][4];
#pragma unroll
    for (int mi = 0; mi < 2; ++mi)
#pragma unroll
        for (int icb = 0; icb < 4; ++icb)
            a[mi][icb] = *(const bf16x8*)(Asmp + ocofs[mi] + (((rotA[mi] + 2 * icb) & 7) << 3));

    // ---- stage B(h=0): 3168 chunks of 16B ----
#pragma unroll
    for (int i = 0; i < 7; ++i) {
        int k = i * 512 + tid;
        if (k < 3168) {
            int rc = k >> 3;
            int c = rc % 66;
            int g = ((k & 7) - c) & 7;
            dma16(xTb + (size_t)rc * 128 + (g << 3), &ldsB[(size_t)k * 8]);
        }
    }
    __syncthreads();

    for (int hs = 0; hs < 18; ++hs) {
        int s = (hs >= 9) ? hs - 9 : hs;
        int kh = s / 3, kw = s - kh * 3;
        int celladd = kh * 66 + kw;
        const ushort* Anext = Asmp + (size_t)(hs + 1) * 8192;
#pragma unroll
        for (int icb = 0; icb < 4; ++icb) {
            int slotb = (rotB + 2 * icb + kw) & 7;
            bf16x8 bb[2];
#pragma unroll
            for (int ch = 0; ch < 2; ++ch) {
                int cell = CB[ch] + celladd;
                bb[ch] = *(const bf16x8*)&ldsB[(cell << 6) + (slotb << 3)];
            }
#pragma unroll
            for (int mi = 0; mi < 2; ++mi)
#pragma unroll
                for (int ch = 0; ch < 2; ++ch)
                    acc[mi][ch] = __builtin_amdgcn_mfma_f32_32x32x16_bf16(a[mi][icb], bb[ch], acc[mi][ch], 0, 0, 0);
            // prefetch this frag for next tap (regs just freed)
            if (hs < 17) {
#pragma unroll
                for (int mi = 0; mi < 2; ++mi)
                    a[mi][icb] = *(const bf16x8*)(Anext + ocofs[mi] + (((rotA[mi] + 2 * icb) & 7) << 3));
            }
        }
        if (hs == 8) {
            __syncthreads();
#pragma unroll
            for (int i = 0; i < 7; ++i) {
                int k = i * 512 + tid;
                if (k < 3168) {
                    int rc = k >> 3;
                    int c = rc % 66;
                    int g = ((k & 7) - c) & 7;
                    dma16(xTb + (size_t)rc * 128 + 64 + (g << 3), &ldsB[(size_t)k * 8]);
                }
            }
            __syncthreads();
        }
    }

    // ---- epilogue: + att@bias, store ----
    float a0 = att[b * 4 + 0], a1 = att[b * 4 + 1], a2 = att[b * 4 + 2], a3 = att[b * 4 + 3];
    int y = y0 + wn;
#pragma unroll
    for (int mi = 0; mi < 2; ++mi)
#pragma unroll
        for (int q = 0; q < 16; ++q) {
            int oc = wm * 64 + mi * 32 + (q & 3) + 8 * (q >> 2) + 4 * lhi;
            float ab = a0 * bias[oc] + a1 * bias[128 + oc] + a2 * bias[256 + oc] + a3 * bias[384 + oc];
#pragma unroll
            for (int ch = 0; ch < 2; ++ch)
                out[(((size_t)b * 128 + oc) * 64 + y) * 64 + ch * 32 + l31] = acc[mi][ch][q] + ab;
        }
}

// ---------------------------------------------------------------------------
extern "C" void kernel_launch(void* const* d_in, const int* in_sizes, int n_in,
                              void* d_out, int out_size, void* d_ws, size_t ws_size,
                              hipStream_t stream) {
    const float* x      = (const float*)d_in[0];
    const float* weight = (const float*)d_in[1];
    const float* bias   = (const float*)d_in[2];
    const float* se_w1  = (const float*)d_in[3];
    const float* gn1_s  = (const float*)d_in[4];
    const float* gn1_b  = (const float*)d_in[5];
    const float* se_w2  = (const float*)d_in[6];
    const float* gn2_s  = (const float*)d_in[7];
    const float* gn2_b  = (const float*)d_in[8];
    float* out = (float*)d_out;

    float*  att     = (float*)((char*)d_ws + 16384);            // 512 B
    float*  partial = (float*)((char*)d_ws + 65536);            // 1 MB (consumed by sefuse, then reused)
    ushort* aggw    = (ushort*)((char*)d_ws + 65536);           // 9.44 MB (written after sefuse reads partial)
    ushort* xT      = (ushort*)((char*)d_ws + 10485760);        // 35.7 MB

    transpose_kernel<<<2048, 256, 0, stream>>>(x, xT, partial);
    sefuse_kernel<<<32, 256, 0, stream>>>(partial, se_w1, gn1_s, gn1_b, se_w2, gn2_s, gn2_b, att);
    aggw_kernel<<<288, 256, 0, stream>>>(weight, att, aggw);
    conv_kernel<<<512, 512, 0, stream>>>(xT, aggw, att, bias, out);
}

// Round 7
// 102.435 us; speedup vs baseline: 1.0246x; 1.0246x over previous
//
#include <hip/hip_runtime.h>
#include <hip/hip_bf16.h>
#include <math.h>
#include <stdint.h>

#define EPS 1e-5f

typedef __attribute__((ext_vector_type(8))) short bf16x8;
typedef __attribute__((ext_vector_type(16))) float f32x16;

__device__ __forceinline__ ushort f2bf(float f) {
    union { float f; unsigned u; } v; v.f = f;
    unsigned r = (v.u + 0x7FFFu + ((v.u >> 16) & 1u)) >> 16;
    return (ushort)r;
}

__device__ __forceinline__ void dma16(const void* g, void* l) {
    __builtin_amdgcn_global_load_lds(
        (__attribute__((address_space(1))) const void*)(uintptr_t)g,
        (__attribute__((address_space(3))) void*)(uintptr_t)l,
        16, 0, 0);
}

// ---------------------------------------------------------------------------
// Kernel 1: transpose x -> xT[b][y 66][c 66][ic 128] bf16 (borders zero),
// plus pooling partials [b][y][ic].  grid = 2048, XCD-grouped by sample.
// ---------------------------------------------------------------------------
__global__ __launch_bounds__(256) void transpose_kernel(const float* __restrict__ x,
                                                        ushort* __restrict__ xT,
                                                        float* __restrict__ partial) {
    __shared__ float T2[64][132];
    int bid = blockIdx.x;
    int b = (bid & 7) * 4 + (bid >> 9);
    int y = (bid >> 3) & 63;
    int t = threadIdx.x;

    int ic2 = t >> 1, half = t & 1;
    const float4* src = (const float4*)(x + (((size_t)b * 128 + ic2) * 64 + y) * 64 + half * 32);
    float s = 0.f;
#pragma unroll
    for (int i = 0; i < 8; ++i) {
        float4 v = src[i];
        int c0 = half * 32 + i * 4;
        T2[c0][ic2] = v.x; T2[c0 + 1][ic2] = v.y; T2[c0 + 2][ic2] = v.z; T2[c0 + 3][ic2] = v.w;
        s += v.x + v.y + v.z + v.w;
    }
    s += __shfl_xor(s, 1, 64);
    if (half == 0) partial[((size_t)b * 64 + y) * 128 + ic2] = s;
    __syncthreads();

    int col = t >> 2, icq = t & 3;
    const float4* row = (const float4*)&T2[col][icq * 32];
    uint pk[16];
#pragma unroll
    for (int m = 0; m < 8; ++m) {
        float4 v = row[m];
        pk[2 * m]     = (uint)f2bf(v.x) | ((uint)f2bf(v.y) << 16);
        pk[2 * m + 1] = (uint)f2bf(v.z) | ((uint)f2bf(v.w) << 16);
    }
    ushort* dst = xT + (((size_t)(b * 66 + y + 1)) * 66 + col + 1) * 128 + icq * 32;
    ((uint4*)dst)[0] = make_uint4(pk[0], pk[1], pk[2], pk[3]);
    ((uint4*)dst)[1] = make_uint4(pk[4], pk[5], pk[6], pk[7]);
    ((uint4*)dst)[2] = make_uint4(pk[8], pk[9], pk[10], pk[11]);
    ((uint4*)dst)[3] = make_uint4(pk[12], pk[13], pk[14], pk[15]);

    uint4 z = make_uint4(0, 0, 0, 0);
    if (y == 0) {
        uint4* row0 = (uint4*)(xT + ((size_t)b * 66 + 0) * 66 * 128);
        for (int i = t; i < 1056; i += 256) row0[i] = z;
    }
    if (y == 63) {
        uint4* row65 = (uint4*)(xT + ((size_t)b * 66 + 65) * 66 * 128);
        for (int i = t; i < 1056; i += 256) row65[i] = z;
    }
    if (t < 32) {
        int c = (t >> 4) * 65;
        int i = t & 15;
        *(uint4*)(xT + (((size_t)(b * 66 + y + 1)) * 66 + c) * 128 + i * 8) = z;
    }
}

// ---------------------------------------------------------------------------
// Kernel 2: fused reduce + SE MLP -> att[32,4].  grid = 32.
// ---------------------------------------------------------------------------
__global__ __launch_bounds__(256) void sefuse_kernel(const float* __restrict__ partial,
                                                     const float* __restrict__ se_w1,
                                                     const float* __restrict__ gn1_s, const float* __restrict__ gn1_b,
                                                     const float* __restrict__ se_w2,
                                                     const float* __restrict__ gn2_s, const float* __restrict__ gn2_b,
                                                     float* __restrict__ att) {
    __shared__ float sA[256];
    __shared__ float pl[128];
    __shared__ float h1s[8];
    int b = blockIdx.x;
    int t = threadIdx.x;
    int ic = t & 127, hf = t >> 7;

    const float* p = partial + ((size_t)b * 64 + hf * 32) * 128 + ic;
    float s = 0.f;
#pragma unroll
    for (int k = 0; k < 32; ++k) s += p[k * 128];
    sA[t] = s;
    __syncthreads();
    if (t < 128) pl[t] = (sA[t] + sA[t + 128]) * (1.0f / 4096.0f);
    __syncthreads();
    if (t < 8) {
        float s1 = 0.f;
        for (int c = 0; c < 128; ++c) s1 += pl[c] * se_w1[t * 128 + c];
        h1s[t] = s1;
    }
    __syncthreads();
    if (t == 0) {
        float h1[8];
#pragma unroll
        for (int j = 0; j < 8; ++j) h1[j] = h1s[j];
        float m = 0.f;
#pragma unroll
        for (int j = 0; j < 8; ++j) m += h1[j];
        m *= 0.125f;
        float var = 0.f;
#pragma unroll
        for (int j = 0; j < 8; ++j) { float d = h1[j] - m; var += d * d; }
        var *= 0.125f;
        float inv = rsqrtf(var + EPS);
#pragma unroll
        for (int j = 0; j < 8; ++j) {
            float tt = (h1[j] - m) * inv * gn1_s[j] + gn1_b[j];
            float sp = (tt > 20.f) ? tt : log1pf(expf(tt));
            h1[j] = tt * tanhf(sp);
        }
        float h2[4];
#pragma unroll
        for (int k = 0; k < 4; ++k) {
            float s2 = 0.f;
#pragma unroll
            for (int j = 0; j < 8; ++j) s2 += h1[j] * se_w2[k * 8 + j];
            h2[k] = s2;
        }
        float m2 = 0.25f * (h2[0] + h2[1] + h2[2] + h2[3]);
        float v2 = 0.f;
#pragma unroll
        for (int k = 0; k < 4; ++k) { float d = h2[k] - m2; v2 += d * d; }
        v2 *= 0.25f;
        float inv2 = rsqrtf(v2 + EPS);
#pragma unroll
        for (int k = 0; k < 4; ++k) {
            float tt = (h2[k] - m2) * inv2 * gn2_s[k] + gn2_b[k];
            att[b * 4 + k] = 1.0f / (1.0f + expf(-tt));
        }
    }
}

// ---------------------------------------------------------------------------
// Kernel 3: aggregate weights -> bf16, rotated-chunk A layout.
// Per (b, tap=h*9+s): 16 KB block of 1024 chunks (16B). Chunk for (oc, g):
// index = oc*8 + ((g + oc) & 7), content = ic [h*64+g*8, +8) of row oc.
// ---------------------------------------------------------------------------
__global__ __launch_bounds__(256) void aggw_kernel(const float* __restrict__ weight,
                                                   const float* __restrict__ att,
                                                   ushort* __restrict__ aggw) {
    int tq = (blockIdx.x % 72) * 256 + threadIdx.x;   // chunk id in sample: 0..18431
    int rep = blockIdx.x / 72;                         // samples rep*8..rep*8+7
    int tap = tq >> 10;
    int within = tq & 1023;
    int oc = within >> 3;
    int p = within & 7;
    int g = (p - oc) & 7;
    int h = tap / 9, s = tap % 9;
    int ic0 = h * 64 + g * 8;

    float wv[4][8];
#pragma unroll
    for (int k = 0; k < 4; ++k)
#pragma unroll
        for (int j = 0; j < 8; ++j)
            wv[k][j] = weight[(((size_t)(k * 128 + oc)) * 128 + ic0 + j) * 9 + s];

    for (int b = rep * 8; b < rep * 8 + 8; ++b) {
        float a0 = att[b * 4 + 0], a1 = att[b * 4 + 1], a2 = att[b * 4 + 2], a3 = att[b * 4 + 3];
        uint pk[4];
#pragma unroll
        for (int q = 0; q < 4; ++q) {
            float f0 = a0 * wv[0][2 * q] + a1 * wv[1][2 * q] + a2 * wv[2][2 * q] + a3 * wv[3][2 * q];
            float f1 = a0 * wv[0][2 * q + 1] + a1 * wv[1][2 * q + 1] + a2 * wv[2][2 * q + 1] + a3 * wv[3][2 * q + 1];
            pk[q] = (uint)f2bf(f0) | ((uint)f2bf(f1) << 16);
        }
        *(uint4*)(aggw + (size_t)b * 147456 + (size_t)tq * 8) = make_uint4(pk[0], pk[1], pk[2], pk[3]);
    }
}

// ---------------------------------------------------------------------------
// Kernel 4: implicit-GEMM conv, mfma_f32_32x32x16_bf16, quarter-ic pipeline.
// grid 512 = 32 b * 16 tiles (4 rows); block 256 = 4 waves (wm: oc-64, wn: row-pair).
// Wave = 64 oc x 128 px, acc[2][4].  LDS: 2 x 25344 B quarter buffers (32 ic),
// double-buffered: stage q+1 issued BEFORE computing q; 1 barrier/quarter.
// A: 2-tap-lookahead register ring aR[3][2][2].
// ---------------------------------------------------------------------------
__global__ __launch_bounds__(256, 2) void conv_kernel(const ushort* __restrict__ xT,
                                                      const ushort* __restrict__ aggw,
                                                      const float* __restrict__ att,
                                                      const float* __restrict__ bias,
                                                      float* __restrict__ out) {
    __shared__ ushort ldsB[2][12672];                 // 2 x 25344 B

    int bid = blockIdx.x;
    int xcd = bid & 7;
    int idx = bid >> 3;
    int b = xcd * 4 + (idx >> 4);
    int tile = idx & 15;
    int y0 = tile * 4;

    int tid = threadIdx.x;
    int l = tid & 63, w = tid >> 6;
    int wm = w >> 1, wn = w & 1;
    int l31 = l & 31, lhi = l >> 5;

    const ushort* xTb = xT + ((size_t)(b * 66 + y0)) * 66 * 128;  // halo rows y0..y0+5
    const ushort* Asmp = aggw + (size_t)b * 147456;

    int ocofs[2], rotA[2];
#pragma unroll
    for (int mi = 0; mi < 2; ++mi) {
        int oc = wm * 64 + mi * 32 + l31;
        ocofs[mi] = oc * 64;
        rotA[mi] = (lhi + oc) & 7;
    }

    f32x16 acc[2][4];
#pragma unroll
    for (int mi = 0; mi < 2; ++mi)
#pragma unroll
        for (int nb = 0; nb < 4; ++nb)
#pragma unroll
            for (int q = 0; q < 16; ++q) acc[mi][nb][q] = 0.f;

    // A ring: [s%3][ib][mi]
    bf16x8 aR[3][2][2];

    // A load for quarter Q, tap S, slot R
#define LOADA(R, Q, S)                                                                       \
    {                                                                                        \
        const ushort* tb_ = Asmp + (size_t)((((Q) >> 1) * 9 + (S))) * 8192;                  \
        _Pragma("unroll")                                                                    \
        for (int ib_ = 0; ib_ < 2; ++ib_)                                                    \
            _Pragma("unroll")                                                                \
            for (int mi_ = 0; mi_ < 2; ++mi_)                                                \
                aR[R][ib_][mi_] = *(const bf16x8*)(tb_ + ocofs[mi_] +                        \
                    (((rotA[mi_] + 4 * ((Q) & 1) + 2 * ib_) & 7) << 3));                     \
    }

    // stage quarter Q (ic 32Q..32Q+31) into buffer BUF: 1584 chunks of 16B
#define STAGE(Q, BUF)                                                                        \
    {                                                                                        \
        _Pragma("unroll")                                                                    \
        for (int i_ = 0; i_ < 7; ++i_) {                                                     \
            int k_ = i_ * 256 + tid;                                                         \
            if (k_ < 1584) {                                                                 \
                int rc_ = k_ >> 2;                                                           \
                int p_ = k_ & 3;                                                             \
                int c_ = rc_ % 66;                                                           \
                int g_ = (p_ - c_ - (c_ >> 2)) & 3;                                          \
                dma16(xTb + (size_t)rc_ * 128 + (Q) * 32 + (g_ << 3),                        \
                      &ldsB[BUF][(size_t)k_ * 8]);                                           \
            }                                                                                \
        }                                                                                    \
    }

    // ---- prologue ----
    STAGE(0, 0);
    LOADA(0, 0, 0);
    LOADA(1, 0, 1);
    __syncthreads();

    for (int q = 0; q < 4; ++q) {
        int cur = q & 1;
        if (q < 3) {
            if (cur) { STAGE(q + 1, 0); } else { STAGE(q + 1, 1); }
        }
        const ushort* buf = ldsB[cur];
#pragma unroll
        for (int s = 0; s < 9; ++s) {
            const int kh = s / 3, kw = s - kh * 3;
            // ---- ib = 0 ----
            {
                bf16x8 bb[4];
#pragma unroll
                for (int nb = 0; nb < 4; ++nb) {
                    int r = 2 * wn + (nb >> 1) + kh;
                    int c = (nb & 1) * 32 + l31 + kw;
                    int p = (lhi + c + (c >> 2)) & 3;
                    bb[nb] = *(const bf16x8*)&buf[((r * 66 + c) << 5) + (p << 3)];
                }
                __builtin_amdgcn_s_setprio(1);
#pragma unroll
                for (int mi = 0; mi < 2; ++mi)
#pragma unroll
                    for (int nb = 0; nb < 4; ++nb)
                        acc[mi][nb] = __builtin_amdgcn_mfma_f32_32x32x16_bf16(aR[s % 3][0][mi], bb[nb], acc[mi][nb], 0, 0, 0);
                __builtin_amdgcn_s_setprio(0);
            }
            // ---- A prefetch: global tap G+2 ----
            if (q < 3 || s < 7) {
                if (s < 7) { LOADA((s + 2) % 3, q, s + 2); }
                else if (s == 7) { LOADA(0, q + 1, 0); }
                else { LOADA(1, q + 1, 1); }
            }
            // ---- ib = 1 ----
            {
                bf16x8 bb[4];
#pragma unroll
                for (int nb = 0; nb < 4; ++nb) {
                    int r = 2 * wn + (nb >> 1) + kh;
                    int c = (nb & 1) * 32 + l31 + kw;
                    int p = (2 + lhi + c + (c >> 2)) & 3;
                    bb[nb] = *(const bf16x8*)&buf[((r * 66 + c) << 5) + (p << 3)];
                }
                __builtin_amdgcn_s_setprio(1);
#pragma unroll
                for (int mi = 0; mi < 2; ++mi)
#pragma unroll
                    for (int nb = 0; nb < 4; ++nb)
                        acc[mi][nb] = __builtin_amdgcn_mfma_f32_32x32x16_bf16(aR[s % 3][1][mi], bb[nb], acc[mi][nb], 0, 0, 0);
                __builtin_amdgcn_s_setprio(0);
            }
        }
        __syncthreads();
    }

    // ---- epilogue: + att@bias, store ----
    float a0 = att[b * 4 + 0], a1 = att[b * 4 + 1], a2 = att[b * 4 + 2], a3 = att[b * 4 + 3];
#pragma unroll
    for (int mi = 0; mi < 2; ++mi)
#pragma unroll
        for (int q = 0; q < 16; ++q) {
            int oc = wm * 64 + mi * 32 + (q & 3) + 8 * (q >> 2) + 4 * lhi;
            float ab = a0 * bias[oc] + a1 * bias[128 + oc] + a2 * bias[256 + oc] + a3 * bias[384 + oc];
#pragma unroll
            for (int nb = 0; nb < 4; ++nb) {
                int y = y0 + 2 * wn + (nb >> 1);
                out[(((size_t)b * 128 + oc) * 64 + y) * 64 + (nb & 1) * 32 + l31] = acc[mi][nb][q] + ab;
            }
        }
#undef LOADA
#undef STAGE
}

// ---------------------------------------------------------------------------
extern "C" void kernel_launch(void* const* d_in, const int* in_sizes, int n_in,
                              void* d_out, int out_size, void* d_ws, size_t ws_size,
                              hipStream_t stream) {
    const float* x      = (const float*)d_in[0];
    const float* weight = (const float*)d_in[1];
    const float* bias   = (const float*)d_in[2];
    const float* se_w1  = (const float*)d_in[3];
    const float* gn1_s  = (const float*)d_in[4];
    const float* gn1_b  = (const float*)d_in[5];
    const float* se_w2  = (const float*)d_in[6];
    const float* gn2_s  = (const float*)d_in[7];
    const float* gn2_b  = (const float*)d_in[8];
    float* out = (float*)d_out;

    float*  att     = (float*)((char*)d_ws + 16384);            // 512 B
    float*  partial = (float*)((char*)d_ws + 65536);            // 1 MB (consumed by sefuse)
    ushort* aggw    = (ushort*)((char*)d_ws + 65536);           // 9.44 MB (written after sefuse)
    ushort* xT      = (ushort*)((char*)d_ws + 10485760);        // 35.7 MB

    transpose_kernel<<<2048, 256, 0, stream>>>(x, xT, partial);
    sefuse_kernel<<<32, 256, 0, stream>>>(partial, se_w1, gn1_s, gn1_b, se_w2, gn2_s, gn2_b, att);
    aggw_kernel<<<288, 256, 0, stream>>>(weight, att, aggw);
    conv_kernel<<<512, 256, 0, stream>>>(xT, aggw, att, bias, out);
}

// Round 8
// 92.694 us; speedup vs baseline: 1.1323x; 1.1051x over previous
//
#include <hip/hip_runtime.h>
#include <hip/hip_bf16.h>
#include <math.h>
#include <stdint.h>

#define EPS 1e-5f

typedef __attribute__((ext_vector_type(8))) short bf16x8;
typedef __attribute__((ext_vector_type(16))) float f32x16;

__device__ __forceinline__ ushort f2bf(float f) {
    union { float f; unsigned u; } v; v.f = f;
    unsigned r = (v.u + 0x7FFFu + ((v.u >> 16) & 1u)) >> 16;
    return (ushort)r;
}

__device__ __forceinline__ void dma16(const void* g, void* l) {
    __builtin_amdgcn_global_load_lds(
        (__attribute__((address_space(1))) const void*)(uintptr_t)g,
        (__attribute__((address_space(3))) void*)(uintptr_t)l,
        16, 0, 0);
}

// ---------------------------------------------------------------------------
// Kernel 1: transpose x -> xT[b][y 66][c 66][ic 128] bf16 (borders zero),
// plus pooled accumulation via atomics.  grid = 2048, XCD-grouped by sample.
// ---------------------------------------------------------------------------
__global__ __launch_bounds__(256) void transpose_kernel(const float* __restrict__ x,
                                                        ushort* __restrict__ xT,
                                                        float* __restrict__ pooled) {
    __shared__ float T2[64][132];
    int bid = blockIdx.x;
    int b = (bid & 7) * 4 + (bid >> 9);
    int y = (bid >> 3) & 63;
    int t = threadIdx.x;

    int ic2 = t >> 1, half = t & 1;
    const float4* src = (const float4*)(x + (((size_t)b * 128 + ic2) * 64 + y) * 64 + half * 32);
    float s = 0.f;
#pragma unroll
    for (int i = 0; i < 8; ++i) {
        float4 v = src[i];
        int c0 = half * 32 + i * 4;
        T2[c0][ic2] = v.x; T2[c0 + 1][ic2] = v.y; T2[c0 + 2][ic2] = v.z; T2[c0 + 3][ic2] = v.w;
        s += v.x + v.y + v.z + v.w;
    }
    s += __shfl_xor(s, 1, 64);
    if (half == 0) atomicAdd(&pooled[b * 128 + ic2], s * (1.0f / 4096.0f));
    __syncthreads();

    int col = t >> 2, icq = t & 3;
    const float4* row = (const float4*)&T2[col][icq * 32];
    uint pk[16];
#pragma unroll
    for (int m = 0; m < 8; ++m) {
        float4 v = row[m];
        pk[2 * m]     = (uint)f2bf(v.x) | ((uint)f2bf(v.y) << 16);
        pk[2 * m + 1] = (uint)f2bf(v.z) | ((uint)f2bf(v.w) << 16);
    }
    ushort* dst = xT + (((size_t)(b * 66 + y + 1)) * 66 + col + 1) * 128 + icq * 32;
    ((uint4*)dst)[0] = make_uint4(pk[0], pk[1], pk[2], pk[3]);
    ((uint4*)dst)[1] = make_uint4(pk[4], pk[5], pk[6], pk[7]);
    ((uint4*)dst)[2] = make_uint4(pk[8], pk[9], pk[10], pk[11]);
    ((uint4*)dst)[3] = make_uint4(pk[12], pk[13], pk[14], pk[15]);

    uint4 z = make_uint4(0, 0, 0, 0);
    if (y == 0) {
        uint4* row0 = (uint4*)(xT + ((size_t)b * 66 + 0) * 66 * 128);
        for (int i = t; i < 1056; i += 256) row0[i] = z;
    }
    if (y == 63) {
        uint4* row65 = (uint4*)(xT + ((size_t)b * 66 + 65) * 66 * 128);
        for (int i = t; i < 1056; i += 256) row65[i] = z;
    }
    if (t < 32) {
        int c = (t >> 4) * 65;
        int i = t & 15;
        *(uint4*)(xT + (((size_t)(b * 66 + y + 1)) * 66 + c) * 128 + i * 8) = z;
    }
}

// ---------------------------------------------------------------------------
// Kernel 2: fused SE MLP + weight aggregation.
// Each block (288 = 4 reps x 72) computes att for its rep's 8 samples from
// pooled (redundantly across the 72 blocks), then does the aggw chunk work.
// A layout (unchanged): per (b, tap): 1024 chunks; chunk idx = oc*8+((g+oc)&7),
// content = ic [h*64+g*8, +8) of row oc.
// ---------------------------------------------------------------------------
__global__ __launch_bounds__(256) void aggw_kernel(const float* __restrict__ weight,
                                                   const float* __restrict__ pooled,
                                                   const float* __restrict__ se_w1,
                                                   const float* __restrict__ gn1_s, const float* __restrict__ gn1_b,
                                                   const float* __restrict__ se_w2,
                                                   const float* __restrict__ gn2_s, const float* __restrict__ gn2_b,
                                                   float* __restrict__ att_out,
                                                   ushort* __restrict__ aggw) {
    __shared__ float pl[8][128];
    __shared__ float h1s[8][8];
    __shared__ float att_s[8][4];
    int blk = blockIdx.x;
    int rep = blk / 72;
    int t = threadIdx.x;

    // load pooled for the 8 samples
#pragma unroll
    for (int u = 0; u < 4; ++u) {
        int pid = u * 256 + t;
        int bl = pid >> 7, ic = pid & 127;
        pl[bl][ic] = pooled[(rep * 8 + bl) * 128 + ic];
    }
    __syncthreads();
    if (t < 64) {
        int bl = t >> 3, jj = t & 7;
        float s1 = 0.f;
        for (int c = 0; c < 128; ++c) s1 += pl[bl][c] * se_w1[jj * 128 + c];
        h1s[bl][jj] = s1;
    }
    __syncthreads();
    if (t < 8) {
        float h1[8];
#pragma unroll
        for (int j = 0; j < 8; ++j) h1[j] = h1s[t][j];
        float m = 0.f;
#pragma unroll
        for (int j = 0; j < 8; ++j) m += h1[j];
        m *= 0.125f;
        float var = 0.f;
#pragma unroll
        for (int j = 0; j < 8; ++j) { float d = h1[j] - m; var += d * d; }
        var *= 0.125f;
        float inv = rsqrtf(var + EPS);
#pragma unroll
        for (int j = 0; j < 8; ++j) {
            float tt = (h1[j] - m) * inv * gn1_s[j] + gn1_b[j];
            float sp = (tt > 20.f) ? tt : log1pf(expf(tt));
            h1[j] = tt * tanhf(sp);
        }
        float h2[4];
#pragma unroll
        for (int k = 0; k < 4; ++k) {
            float s2 = 0.f;
#pragma unroll
            for (int j = 0; j < 8; ++j) s2 += h1[j] * se_w2[k * 8 + j];
            h2[k] = s2;
        }
        float m2 = 0.25f * (h2[0] + h2[1] + h2[2] + h2[3]);
        float v2 = 0.f;
#pragma unroll
        for (int k = 0; k < 4; ++k) { float d = h2[k] - m2; v2 += d * d; }
        v2 *= 0.25f;
        float inv2 = rsqrtf(v2 + EPS);
#pragma unroll
        for (int k = 0; k < 4; ++k) {
            float tt = (h2[k] - m2) * inv2 * gn2_s[k] + gn2_b[k];
            att_s[t][k] = 1.0f / (1.0f + expf(-tt));
        }
    }
    __syncthreads();

    if ((blk % 72) == 0 && t < 32) att_out[rep * 32 + t] = att_s[t >> 2][t & 3];

    // original aggw chunk work
    int tq = (blk % 72) * 256 + t;                     // 0..18431
    int tap = tq >> 10;
    int within = tq & 1023;
    int oc = within >> 3;
    int p = within & 7;
    int g = (p - oc) & 7;
    int h = tap / 9, s = tap % 9;
    int ic0 = h * 64 + g * 8;

    float wv[4][8];
#pragma unroll
    for (int k = 0; k < 4; ++k)
#pragma unroll
        for (int j = 0; j < 8; ++j)
            wv[k][j] = weight[(((size_t)(k * 128 + oc)) * 128 + ic0 + j) * 9 + s];

#pragma unroll
    for (int bl = 0; bl < 8; ++bl) {
        int b = rep * 8 + bl;
        float a0 = att_s[bl][0], a1 = att_s[bl][1], a2 = att_s[bl][2], a3 = att_s[bl][3];
        uint pk[4];
#pragma unroll
        for (int q = 0; q < 4; ++q) {
            float f0 = a0 * wv[0][2 * q] + a1 * wv[1][2 * q] + a2 * wv[2][2 * q] + a3 * wv[3][2 * q];
            float f1 = a0 * wv[0][2 * q + 1] + a1 * wv[1][2 * q + 1] + a2 * wv[2][2 * q + 1] + a3 * wv[3][2 * q + 1];
            pk[q] = (uint)f2bf(f0) | ((uint)f2bf(f1) << 16);
        }
        *(uint4*)(aggw + (size_t)b * 147456 + (size_t)tq * 8) = make_uint4(pk[0], pk[1], pk[2], pk[3]);
    }
}

// ---------------------------------------------------------------------------
// Kernel 3: implicit-GEMM conv, mfma_f32_32x32x16_bf16, 8-row tiles.
// grid 256 = 32 b * 8 tiles -> EXACTLY 1 block/CU, no tail.  block 512 = 8 waves
// (wm: oc-half, wn: row-pair 0..3).  Wave = 64 oc x 128 px, acc[2][4] (r5 per-wave
// schedule unchanged: LDS B w/ rotation slots, A depth-1 register prefetch,
// 3 barriers total).  LDS 84.5 KB single buffer, staged per ic-half.
// ---------------------------------------------------------------------------
__global__ __launch_bounds__(512, 2) void conv_kernel(const ushort* __restrict__ xT,
                                                      const ushort* __restrict__ aggw,
                                                      const float* __restrict__ att,
                                                      const float* __restrict__ bias,
                                                      float* __restrict__ out) {
    __shared__ ushort ldsB[660 * 64];                 // 10 rows x 66 cols x 64 = 84480 B

    int bid = blockIdx.x;
    int xcd = bid & 7;
    int j = bid >> 3;                                  // 0..31
    int b = xcd * 4 + (j >> 3);                        // 4 samples per XCD
    int tile = j & 7;
    int y0 = tile * 8;

    int tid = threadIdx.x;
    int l = tid & 63, w = tid >> 6;
    int wm = w >> 2, wn = w & 3;                       // oc-half; row-pair
    int l31 = l & 31, lhi = l >> 5;

    const ushort* xTb = xT + ((size_t)(b * 66 + y0)) * 66 * 128;  // halo rows y0..y0+9
    const ushort* Asmp = aggw + (size_t)b * 147456;

    int ocofs[2], rotA[2];
#pragma unroll
    for (int mi = 0; mi < 2; ++mi) {
        int oc = wm * 64 + mi * 32 + l31;
        ocofs[mi] = oc * 64;
        rotA[mi] = (lhi + oc) & 7;
    }
    int CB[4];
#pragma unroll
    for (int nb = 0; nb < 4; ++nb)
        CB[nb] = (2 * wn + (nb >> 1)) * 66 + (nb & 1) * 32 + l31;
    int rotB = (l31 + lhi) & 7;

    f32x16 acc[2][4];
#pragma unroll
    for (int mi = 0; mi < 2; ++mi)
#pragma unroll
        for (int nb = 0; nb < 4; ++nb)
#pragma unroll
            for (int q = 0; q < 16; ++q) acc[mi][nb][q] = 0.f;

    // prefetch A tap 0
    bf16x8 a[2][4];
#pragma unroll
    for (int mi = 0; mi < 2; ++mi)
#pragma unroll
        for (int icb = 0; icb < 4; ++icb)
            a[mi][icb] = *(const bf16x8*)(Asmp + ocofs[mi] + (((rotA[mi] + 2 * icb) & 7) << 3));

    // stage h=0: 5280 chunks of 16B
#pragma unroll
    for (int i = 0; i < 11; ++i) {
        int k = i * 512 + tid;
        if (k < 5280) {
            int rc = k >> 3;
            int c = rc % 66;
            int g = ((k & 7) - c) & 7;
            dma16(xTb + (size_t)rc * 128 + (g << 3), &ldsB[(size_t)k * 8]);
        }
    }
    __syncthreads();

    for (int hs = 0; hs < 18; ++hs) {
        int s = (hs >= 9) ? hs - 9 : hs;
        int kh = s / 3, kw = s - kh * 3;
        int celladd = kh * 66 + kw;
        const ushort* Anext = Asmp + (size_t)(hs + 1) * 8192;
#pragma unroll
        for (int icb = 0; icb < 4; ++icb) {
            int slotb = (rotB + 2 * icb + kw) & 7;
            bf16x8 bb[4];
#pragma unroll
            for (int nb = 0; nb < 4; ++nb) {
                int cell = CB[nb] + celladd;
                bb[nb] = *(const bf16x8*)&ldsB[(cell << 6) + (slotb << 3)];
            }
#pragma unroll
            for (int mi = 0; mi < 2; ++mi)
#pragma unroll
                for (int nb = 0; nb < 4; ++nb)
                    acc[mi][nb] = __builtin_amdgcn_mfma_f32_32x32x16_bf16(a[mi][icb], bb[nb], acc[mi][nb], 0, 0, 0);
            if (hs < 17) {
#pragma unroll
                for (int mi = 0; mi < 2; ++mi)
                    a[mi][icb] = *(const bf16x8*)(Anext + ocofs[mi] + (((rotA[mi] + 2 * icb) & 7) << 3));
            }
        }
        if (hs == 8) {
            __syncthreads();
#pragma unroll
            for (int i = 0; i < 11; ++i) {
                int k = i * 512 + tid;
                if (k < 5280) {
                    int rc = k >> 3;
                    int c = rc % 66;
                    int g = ((k & 7) - c) & 7;
                    dma16(xTb + (size_t)rc * 128 + 64 + (g << 3), &ldsB[(size_t)k * 8]);
                }
            }
            __syncthreads();
        }
    }

    // epilogue: + att@bias, store
    float a0 = att[b * 4 + 0], a1 = att[b * 4 + 1], a2 = att[b * 4 + 2], a3 = att[b * 4 + 3];
#pragma unroll
    for (int mi = 0; mi < 2; ++mi)
#pragma unroll
        for (int q = 0; q < 16; ++q) {
            int oc = wm * 64 + mi * 32 + (q & 3) + 8 * (q >> 2) + 4 * lhi;
            float ab = a0 * bias[oc] + a1 * bias[128 + oc] + a2 * bias[256 + oc] + a3 * bias[384 + oc];
#pragma unroll
            for (int nb = 0; nb < 4; ++nb) {
                int y = y0 + 2 * wn + (nb >> 1);
                out[(((size_t)b * 128 + oc) * 64 + y) * 64 + (nb & 1) * 32 + l31] = acc[mi][nb][q] + ab;
            }
        }
}

// ---------------------------------------------------------------------------
extern "C" void kernel_launch(void* const* d_in, const int* in_sizes, int n_in,
                              void* d_out, int out_size, void* d_ws, size_t ws_size,
                              hipStream_t stream) {
    const float* x      = (const float*)d_in[0];
    const float* weight = (const float*)d_in[1];
    const float* bias   = (const float*)d_in[2];
    const float* se_w1  = (const float*)d_in[3];
    const float* gn1_s  = (const float*)d_in[4];
    const float* gn1_b  = (const float*)d_in[5];
    const float* se_w2  = (const float*)d_in[6];
    const float* gn2_s  = (const float*)d_in[7];
    const float* gn2_b  = (const float*)d_in[8];
    float* out = (float*)d_out;

    float*  att    = (float*)d_ws;                              // 512 B
    float*  pooled = (float*)((char*)d_ws + 16384);             // 16 KB
    ushort* aggw   = (ushort*)((char*)d_ws + 65536);            // 9.44 MB
    ushort* xT     = (ushort*)((char*)d_ws + 10485760);         // 35.7 MB

    hipMemsetAsync(pooled, 0, 128 * 32 * sizeof(float), stream);
    transpose_kernel<<<2048, 256, 0, stream>>>(x, xT, pooled);
    aggw_kernel<<<288, 256, 0, stream>>>(weight, pooled, se_w1, gn1_s, gn1_b,
                                         se_w2, gn2_s, gn2_b, att, aggw);
    conv_kernel<<<256, 512, 0, stream>>>(xT, aggw, att, bias, out);
}